// Round 11
// baseline (94.820 us; speedup 1.0000x reference)
//
#include <hip/hip_runtime.h>
#include <stdint.h>
#include <stddef.h>

#define BB 16384
#define CC 500
#define DD 512
#define PADC 512
#define LMARGIN 1.0f
#define EPSQ 1e-12f
#define NKC 16   // K-chunks of 32
#define ROWS 32  // rows per block

typedef __attribute__((ext_vector_type(8))) _Float16 f16x8;
typedef __attribute__((ext_vector_type(4))) _Float16 f16x4;
typedef __attribute__((ext_vector_type(4))) float f32x4;

#define GLOBAL_AS __attribute__((address_space(1)))
#define LDS_AS __attribute__((address_space(3)))

__device__ __forceinline__ void ld_lds16(const void* g, void* l) {
  __builtin_amdgcn_global_load_lds((const GLOBAL_AS void*)g, (LDS_AS void*)l, 16, 0, 0);
}

// ---- prepP: protos fp32 -> protoT f16 in FRAGMENT-LINEAR layout + p2 ----
// unit (cg, kc) at byte (cg*16 + kc)*1024; lane l's 16 B inside a unit =
// B[col = cg*16 + (l&15)][k = kc*32 + (l>>4)*8 .. +7].
__global__ void prepP_kernel(const float* __restrict__ protos,
                             unsigned short* __restrict__ protoT,
                             float* __restrict__ p2,
                             float* __restrict__ out) {
  __shared__ float s_arr[16][17];
  const int cg = blockIdx.x;   // 0..31
  const int t = threadIdx.x;   // 0..255
  const int colin = t & 15;
  const int jb = t >> 4;       // 0..15
  const int col = cg * 16 + colin;
  if (cg == 0 && t == 0) out[0] = 0.f;
  float s = 0.f;
#pragma unroll
  for (int u = 0; u < 4; ++u) {
    const int j8 = jb + u * 16;          // 0..63: 8-float k-unit
    const int kc = j8 >> 2, quad = j8 & 3;
    f32x4 a0 = {0.f, 0.f, 0.f, 0.f}, a1 = a0;
    if (col < CC) {
      const float* src = protos + (size_t)col * DD + j8 * 8;
      a0 = *(const f32x4*)src;
      a1 = *(const f32x4*)(src + 4);
    }
    f16x8 h;
#pragma unroll
    for (int uu = 0; uu < 4; ++uu) {
      h[uu] = (_Float16)a0[uu];
      h[uu + 4] = (_Float16)a1[uu];
      s = fmaf(a0[uu], a0[uu], s);
      s = fmaf(a1[uu], a1[uu], s);
    }
    *(f16x8*)(protoT + (size_t)(cg * 16 + kc) * 512 + (quad * 16 + colin) * 8) = h;
  }
  s_arr[colin][jb] = s;
  __syncthreads();
  if (t < 16) {
    float acc = 0.f;
#pragma unroll
    for (int i = 0; i < 16; ++i) acc += s_arr[t][i];
    p2[cg * 16 + t] = acc;
  }
}

// ---- main: 512 blocks x 512 threads (8 waves); block = 32 rows x 512 cols;
// wave = all 32 rows x 64-col octant; acc 2x4 of 16x16x32.
// A: fp32 staged by global_load_lds into a kc-paged 64 KB LDS buffer in 4
// QUARTER-BATCHES pipelined against the K-loop (DMA(q+1) issued right after
// the barrier that opens quarter q). Fragment reads convert fp32->f16 in
// registers; global-side XOR swizzle (chunk ^ (row&7)) keeps the b128 reads
// at the bank floor. f2 = post-pass over the resident fp32 A. B: fragment-
// linear global->VGPR ring-3/depth-2 (unchanged from R10). 6 barriers. ----
__launch_bounds__(512, 4)
__global__ void main_kernel(const float* __restrict__ feat,
                            const unsigned short* __restrict__ protoT,
                            const float* __restrict__ p2,
                            const int* __restrict__ labels,
                            float* __restrict__ outp) {
  __shared__ __align__(16) unsigned char Afp[NKC * 4096];  // 64 KB fp32 A
  // epilogue scratch aliased into Afp (used only after the f2 read barrier)
  float* redM = (float*)&Afp[0];     // [32 rows][8 w] = 1 KB
  float* redP = (float*)&Afp[1024];  // 1 KB
  float* f2l = (float*)&Afp[2048];   // 128 B

  const int tid = threadIdx.x;
  const int w = tid >> 6;
  const int lane = tid & 63;
  const int lane16 = lane & 15;
  const int quad = lane >> 4;
  const int r0 = blockIdx.x * ROWS;

  // ---- B pointers: unit (cg = w*4+nt, kc) at byte (cg*16+kc)*1024 ----
  const char* bptr[4];
#pragma unroll
  for (int nt = 0; nt < 4; ++nt)
    bptr[nt] = (const char*)protoT + (size_t)(w * 64 + nt * 16) * 1024 + lane * 16;

  // issue B(0), B(1) early (retire during the q0 DMA wait)
  f16x8 bfr[3][4];
#pragma unroll
  for (int nt = 0; nt < 4; ++nt) {
    bfr[0][nt] = *(const f16x8*)(bptr[nt]);
    bfr[1][nt] = *(const f16x8*)(bptr[nt] + 1024);
  }

  // ---- A DMA mapping: region r_idx = e*8 + w (e=0,1) -> kcq = r_idx>>2,
  // row-block rb = r_idx&3. Lane: row R = rb*8 + (lane>>3), slot j = lane&7
  // holds global chunk g = j ^ (R&7)  (R&7 == lane>>3). ----
  const int l3 = lane >> 3, j8 = lane & 7;
  const float* aBase = feat + (size_t)(r0 + l3) * DD + ((j8 ^ l3) << 2);
  char* ldsBase = (char*)Afp + lane * 16;
  const int kcq0 = w >> 2, rb0 = w & 3;            // e = 0
  const int kcq1 = (8 + w) >> 2, rb1 = (8 + w) & 3;  // e = 1

#define DMA_Q(q)                                                            \
  do {                                                                      \
    int kcA = (q) * 4 + kcq0, kcB = (q) * 4 + kcq1;                         \
    ld_lds16(aBase + (size_t)(rb0 * 8) * DD + kcA * 32,                     \
             ldsBase + kcA * 4096 + rb0 * 1024);                            \
    ld_lds16(aBase + (size_t)(rb1 * 8) * DD + kcB * 32,                     \
             ldsBase + kcB * 4096 + rb1 * 1024);                            \
  } while (0)

  DMA_Q(0);

  f32x4 acc[2][4];
#pragma unroll
  for (int mt = 0; mt < 2; ++mt)
#pragma unroll
    for (int nt = 0; nt < 4; ++nt) acc[mt][nt] = (f32x4){0.f, 0.f, 0.f, 0.f};

  __syncthreads();  // barrier 1: A-quarter 0 + B(0,1) landed

  // ---- K-loop: 4 quarters; DMA(q+1) overlaps quarter q's compute ----
  const int r7 = lane16 & 7;
  const int c0 = ((quad * 2) ^ r7) * 16;
  const int c1 = ((quad * 2 + 1) ^ r7) * 16;
#pragma unroll
  for (int qi = 0; qi < 4; ++qi) {
    if (qi < 3) DMA_Q(qi + 1);
#pragma unroll
    for (int j = 0; j < 4; ++j) {
      const int kc = qi * 4 + j;
      if (kc + 2 < NKC) {
#pragma unroll
        for (int nt = 0; nt < 4; ++nt)
          bfr[(kc + 2) % 3][nt] =
              *(const f16x8*)(bptr[nt] + (size_t)(kc + 2) * 1024);
      }
      f16x8 af[2];
#pragma unroll
      for (int mt = 0; mt < 2; ++mt) {
        const unsigned char* ab = Afp + kc * 4096 + (mt * 16 + lane16) * 128;
        f32x4 x0 = *(const f32x4*)(ab + c0);
        f32x4 x1 = *(const f32x4*)(ab + c1);
        f16x8 a;
#pragma unroll
        for (int u = 0; u < 4; ++u) {
          a[u] = (_Float16)x0[u];
          a[u + 4] = (_Float16)x1[u];
        }
        af[mt] = a;
      }
#pragma unroll
      for (int mt = 0; mt < 2; ++mt)
#pragma unroll
        for (int nt = 0; nt < 4; ++nt)
          acc[mt][nt] = __builtin_amdgcn_mfma_f32_16x16x32_f16(
              af[mt], bfr[kc % 3][nt], acc[mt][nt], 0, 0, 0);
    }
    if (qi < 3) __syncthreads();  // barriers 2..4: next quarter's DMA landed
  }
#undef DMA_Q

  // ---- f2 post-pass: thread (row = tid>>4, kc = tid&15) reads 8 slots of
  // its row at its kc (staggered to stay at the bank floor), 16-thread sum ----
  float s = 0.f;
  {
    const int frow = tid >> 4, fkc = tid & 15, t7 = tid & 7;
    const unsigned char* fb = Afp + fkc * 4096 + frow * 128;
#pragma unroll
    for (int si = 0; si < 8; ++si) {
      const int slot = ((si + t7) & 7) * 16;
      f32x4 v = *(const f32x4*)(fb + slot);
      s = fmaf(v[0], v[0], fmaf(v[1], v[1], fmaf(v[2], v[2], fmaf(v[3], v[3], s))));
    }
    s += __shfl_xor(s, 1, 64);
    s += __shfl_xor(s, 2, 64);
    s += __shfl_xor(s, 4, 64);
    s += __shfl_xor(s, 8, 64);
  }
  __syncthreads();  // barrier 5: all Afp reads done -> aliasing safe
  if ((tid & 15) == 0) f2l[tid >> 4] = s;

  // ---- epilogue: q = p2 - 2*dot; masked min/pos over my 64 cols ----
  float p2v[4];
#pragma unroll
  for (int nt = 0; nt < 4; ++nt) p2v[nt] = p2[w * 64 + nt * 16 + lane16];

#pragma unroll
  for (int mt = 0; mt < 2; ++mt) {
#pragma unroll
    for (int i = 0; i < 4; ++i) {
      const int row = mt * 16 + quad * 4 + i;
      const int lb = labels[r0 + row];  // wave-uniform broadcast
      float qm = 1e30f, qp = -1e30f;
#pragma unroll
      for (int nt = 0; nt < 4; ++nt) {
        const int col = w * 64 + nt * 16 + lane16;
        float q = p2v[nt] - 2.f * acc[mt][nt][i];
        bool isPos = (col == lb);
        qp = fmaxf(qp, isPos ? q : -1e30f);
        qm = fminf(qm, (!isPos && col < CC) ? q : 1e30f);
      }
#pragma unroll
      for (int d = 1; d < 16; d <<= 1) {
        qm = fminf(qm, __shfl_xor(qm, d, 64));
        qp = fmaxf(qp, __shfl_xor(qp, d, 64));
      }
      if (lane16 == 0) {
        redM[row * 8 + w] = qm;
        redP[row * 8 + w] = qp;
      }
    }
  }
  __syncthreads();  // barrier 6: partials + f2l visible

  // ---- combine 8 octants per row, sqrt+hinge, block sum, one atomic ----
  if (tid < ROWS) {
    float qm = 1e30f, qp = -1e30f;
#pragma unroll
    for (int j = 0; j < 8; ++j) {
      qm = fminf(qm, redM[tid * 8 + j]);
      qp = fmaxf(qp, redP[tid * 8 + j]);
    }
    float f2 = f2l[tid];
    float dn = sqrtf(fmaxf(f2 + qm, EPSQ));
    float dp = sqrtf(fmaxf(f2 + qp, EPSQ));
    float term = fmaxf(dp - dn + LMARGIN, 0.f);
#pragma unroll
    for (int d = 1; d < 32; d <<= 1) term += __shfl_xor(term, d, 64);
    if (tid == 0) atomicAdd(outp, term * (1.0f / BB));
  }
}

extern "C" void kernel_launch(void* const* d_in, const int* in_sizes, int n_in,
                              void* d_out, int out_size, void* d_ws, size_t ws_size,
                              hipStream_t stream) {
  const float* feat = (const float*)d_in[0];
  const float* protos = (const float*)d_in[1];
  const int* labels = (const int*)d_in[2];
  float* out = (float*)d_out;

  char* ws = (char*)d_ws;
  unsigned short* protoT = (unsigned short*)(ws);   // 512 KB fragment-linear B
  float* p2 = (float*)(ws + (512 << 10));           // 2 KB

  prepP_kernel<<<32, 256, 0, stream>>>(protos, protoT, p2, out);
  main_kernel<<<BB / ROWS, 512, 0, stream>>>(feat, protoT, p2, labels, out);
}